// Round 12
// baseline (6120.996 us; speedup 1.0000x reference)
//
#include <hip/hip_runtime.h>

// ---------------- problem constants ----------------
// B=32, T=250, FEAT=128, CLASSES=25, UNITS=512, CELL=64, HEADS=4, IN_LSTM=409

// ---------------- scratch layout (floats) ----------------
constexpr size_t OFF_FEATP  = 0;                              // [8000][128]
constexpr size_t OFF_WXI    = OFF_FEATP + (size_t)8000 * 128; // [409][2048] gate-interleaved
constexpr size_t OFF_WHI    = OFF_WXI + (size_t)409 * 2048;   // [512][2048]
constexpr size_t OFF_BLI    = OFF_WHI + (size_t)512 * 2048;   // [2048]
constexpr size_t OFF_ZP0    = OFF_BLI + 2048;                 // [2][32][2048] parity
constexpr size_t OFF_ZP1    = OFF_ZP0 + 131072;               // [2][32][2048]
constexpr size_t OFF_OH0    = OFF_ZP1 + 131072;               // [2][32][512]
constexpr size_t OFF_OH1    = OFF_OH0 + 32768;                // [2][32][512]
constexpr size_t OFF_HP0    = OFF_OH1 + 32768;                // [32][320]
constexpr size_t OFF_HP1    = OFF_HP0 + 10240;                // [32][320]
constexpr size_t OFF_OUTPRE = OFF_HP1 + 10240;                // [2][32][512] parity
constexpr size_t OFF_HT     = OFF_OUTPRE + 32768;             // [2][512][32] parity
constexpr size_t OFF_RVT    = OFF_HT + 32768;                 // [2][256][32] parity
constexpr size_t OFF_BAR    = OFF_RVT + 16384;                // counters (4096 ints)
constexpr size_t WS_FLOATS  = OFF_BAR + 4096;

constexpr int DYN_FLOATS = 34816;                 // 136 KB dynamic LDS
constexpr int DYN_BYTES  = DYN_FLOATS * 4;

// counter bases (ints; 8 lines x 64-int stride each)
constexpr int CZP = 0, CHT = 512, COH = 1024, CHP = 1536, CRV = 2048, COP = 2560;

__device__ __forceinline__ float sigm(float x) { return 1.f / (1.f + __expf(-x)); }

__device__ __forceinline__ void sleep_k(int slp) {
  // __builtin_amdgcn_s_sleep needs a literal; dispatch on constant call sites.
  if (slp <= 1) __builtin_amdgcn_s_sleep(1);
  else if (slp == 2) __builtin_amdgcn_s_sleep(2);
  else if (slp == 4) __builtin_amdgcn_s_sleep(4);
  else __builtin_amdgcn_s_sleep(8);
}

// ---- LLC-coherent accesses (bypass L1+L2). Loads batched in asm with the
// waitcnt inside so they cannot be serialized into dependent round-trips.
__device__ __forceinline__ void st_sc(float* p, float v) {
  __hip_atomic_store(p, v, __ATOMIC_RELAXED, __HIP_MEMORY_SCOPE_AGENT);
}
__device__ __forceinline__ float ld_sc(const float* p) {
  return __hip_atomic_load(p, __ATOMIC_RELAXED, __HIP_MEMORY_SCOPE_AGENT);
}
__device__ __forceinline__ void ld8x2_sc(const double* b0, double* v) {
  const double *p0 = b0, *p1 = b0 + 512, *p2 = b0 + 1024, *p3 = b0 + 1536,
               *p4 = b0 + 2048, *p5 = b0 + 2560, *p6 = b0 + 3072, *p7 = b0 + 3584;
  asm volatile(
      "global_load_dwordx2 %0, %8, off sc0 sc1\n\t"
      "global_load_dwordx2 %1, %9, off sc0 sc1\n\t"
      "global_load_dwordx2 %2, %10, off sc0 sc1\n\t"
      "global_load_dwordx2 %3, %11, off sc0 sc1\n\t"
      "global_load_dwordx2 %4, %12, off sc0 sc1\n\t"
      "global_load_dwordx2 %5, %13, off sc0 sc1\n\t"
      "global_load_dwordx2 %6, %14, off sc0 sc1\n\t"
      "global_load_dwordx2 %7, %15, off sc0 sc1\n\t"
      "s_waitcnt vmcnt(0)"
      : "=&v"(v[0]), "=&v"(v[1]), "=&v"(v[2]), "=&v"(v[3]),
        "=&v"(v[4]), "=&v"(v[5]), "=&v"(v[6]), "=&v"(v[7])
      : "v"(p0), "v"(p1), "v"(p2), "v"(p3), "v"(p4), "v"(p5), "v"(p6), "v"(p7)
      : "memory");
}
// 8 rv loads + 2 partial loads, one waitcnt (gates/outpre staging)
__device__ __forceinline__ void ld10x2_sc(const double* b0, const double* z0,
                                          const double* z1, double* v) {
  const double *p0 = b0, *p1 = b0 + 512, *p2 = b0 + 1024, *p3 = b0 + 1536,
               *p4 = b0 + 2048, *p5 = b0 + 2560, *p6 = b0 + 3072, *p7 = b0 + 3584;
  asm volatile(
      "global_load_dwordx2 %0, %10, off sc0 sc1\n\t"
      "global_load_dwordx2 %1, %11, off sc0 sc1\n\t"
      "global_load_dwordx2 %2, %12, off sc0 sc1\n\t"
      "global_load_dwordx2 %3, %13, off sc0 sc1\n\t"
      "global_load_dwordx2 %4, %14, off sc0 sc1\n\t"
      "global_load_dwordx2 %5, %15, off sc0 sc1\n\t"
      "global_load_dwordx2 %6, %16, off sc0 sc1\n\t"
      "global_load_dwordx2 %7, %17, off sc0 sc1\n\t"
      "global_load_dwordx2 %8, %18, off sc0 sc1\n\t"
      "global_load_dwordx2 %9, %19, off sc0 sc1\n\t"
      "s_waitcnt vmcnt(0)"
      : "=&v"(v[0]), "=&v"(v[1]), "=&v"(v[2]), "=&v"(v[3]), "=&v"(v[4]),
        "=&v"(v[5]), "=&v"(v[6]), "=&v"(v[7]), "=&v"(v[8]), "=&v"(v[9])
      : "v"(p0), "v"(p1), "v"(p2), "v"(p3), "v"(p4), "v"(p5), "v"(p6), "v"(p7),
        "v"(z0), "v"(z1)
      : "memory");
}
__device__ __forceinline__ void ldpair_sc(const float* a, const float* b,
                                          float& x, float& y) {
  asm volatile(
      "global_load_dword %0, %2, off sc0 sc1\n\t"
      "global_load_dword %1, %3, off sc0 sc1\n\t"
      "s_waitcnt vmcnt(0)"
      : "=&v"(x), "=&v"(y) : "v"(a), "v"(b) : "memory");
}
// counter poll: sum of 8 lines, single batched round trip
__device__ __forceinline__ int sum8_bar(const int* b) {
  int v0, v1, v2, v3, v4, v5, v6, v7;
  asm volatile(
      "global_load_dword %0, %8, off sc0 sc1\n\t"
      "global_load_dword %1, %9, off sc0 sc1\n\t"
      "global_load_dword %2, %10, off sc0 sc1\n\t"
      "global_load_dword %3, %11, off sc0 sc1\n\t"
      "global_load_dword %4, %12, off sc0 sc1\n\t"
      "global_load_dword %5, %13, off sc0 sc1\n\t"
      "global_load_dword %6, %14, off sc0 sc1\n\t"
      "global_load_dword %7, %15, off sc0 sc1\n\t"
      "s_waitcnt vmcnt(0)"
      : "=&v"(v0), "=&v"(v1), "=&v"(v2), "=&v"(v3),
        "=&v"(v4), "=&v"(v5), "=&v"(v6), "=&v"(v7)
      : "v"(b), "v"(b + 64), "v"(b + 128), "v"(b + 192),
        "v"(b + 256), "v"(b + 320), "v"(b + 384), "v"(b + 448)
      : "memory");
  return ((v0 + v1) + (v2 + v3)) + ((v4 + v5) + (v6 + v7));
}

// ---------------- weight re-layout: gate-interleaved Wx/Wh/bl ----------------
__global__ __launch_bounds__(256) void prep_kernel(const float* __restrict__ Wx,
                                                   const float* __restrict__ Wh,
                                                   const float* __restrict__ bl,
                                                   float* __restrict__ ws) {
  float* WXI = ws + OFF_WXI;
  float* WHI = ws + OFF_WHI;
  float* BLI = ws + OFF_BLI;
  const int total = 409 * 2048 + 512 * 2048 + 2048;
  for (int idx = blockIdx.x * blockDim.x + threadIdx.x; idx < total;
       idx += gridDim.x * blockDim.x) {
    if (idx < 409 * 2048) {
      int k = idx >> 11, cc = idx & 2047;
      WXI[idx] = Wx[(size_t)k * 2048 + (cc & 3) * 512 + (cc >> 2)];
    } else if (idx < 409 * 2048 + 512 * 2048) {
      int j = idx - 409 * 2048;
      int k = j >> 11, cc = j & 2047;
      WHI[j] = Wh[(size_t)k * 2048 + (cc & 3) * 512 + (cc >> 2)];
    } else {
      int cc = idx - (409 * 2048 + 512 * 2048);
      BLI[cc] = bl[(cc & 3) * 512 + (cc >> 2)];
    }
  }
}

// ---------------- conv stack (validated) ----------------
__global__ __launch_bounds__(128) void conv_kernel(
    const float* __restrict__ img,
    const float* __restrict__ k1, const float* __restrict__ cb1, const float* __restrict__ g1,
    const float* __restrict__ be1, const float* __restrict__ mm1, const float* __restrict__ mv1,
    const float* __restrict__ k2, const float* __restrict__ cb2, const float* __restrict__ g2,
    const float* __restrict__ be2, const float* __restrict__ mm2, const float* __restrict__ mv2,
    const float* __restrict__ k3, const float* __restrict__ cb3, const float* __restrict__ g3,
    const float* __restrict__ be3, const float* __restrict__ mm3, const float* __restrict__ mv3,
    float* __restrict__ ws) {
  __shared__ float s_in[784];
  __shared__ float s_y1[13 * 13 * 8];
  __shared__ float s_y2[6 * 6 * 16];
  __shared__ float s_k1[72], s_k2[1152], s_k3[4608];
  __shared__ float s_s1[8], s_b1[8], s_s2[16], s_b2[16], s_s3[32], s_b3[32];
  float* FEATP = ws + OFF_FEATP;
  const int n = blockIdx.x, tid = threadIdx.x;
  const float* ip = img + (size_t)n * 784;
  for (int i = tid; i < 784; i += 128) s_in[i] = ip[i];
  for (int i = tid; i < 72; i += 128) s_k1[i] = k1[i];
  for (int i = tid; i < 1152; i += 128) s_k2[i] = k2[i];
  for (int i = tid; i < 4608; i += 128) s_k3[i] = k3[i];
  if (tid < 8) {
    float s = g1[tid] * rsqrtf(mv1[tid] + 1e-3f);
    s_s1[tid] = s; s_b1[tid] = (cb1[tid] - mm1[tid]) * s + be1[tid];
  } else if (tid >= 32 && tid < 48) {
    int c = tid - 32;
    float s = g2[c] * rsqrtf(mv2[c] + 1e-3f);
    s_s2[c] = s; s_b2[c] = (cb2[c] - mm2[c]) * s + be2[c];
  } else if (tid >= 64 && tid < 96) {
    int c = tid - 64;
    float s = g3[c] * rsqrtf(mv3[c] + 1e-3f);
    s_s3[c] = s; s_b3[c] = (cb3[c] - mm3[c]) * s + be3[c];
  }
  __syncthreads();
  for (int idx = tid; idx < 13 * 13 * 8; idx += 128) {
    int co = idx & 7, pos = idx >> 3;
    int j = pos % 13, i = pos / 13;
    float acc = 0.f;
    #pragma unroll
    for (int ky = 0; ky < 3; ++ky)
      #pragma unroll
      for (int kx = 0; kx < 3; ++kx)
        acc += s_in[(2 * i + ky) * 28 + (2 * j + kx)] * s_k1[(ky * 3 + kx) * 8 + co];
    float v = acc * s_s1[co] + s_b1[co];
    s_y1[idx] = v > 0.f ? v : 0.f;
  }
  __syncthreads();
  for (int idx = tid; idx < 6 * 6 * 16; idx += 128) {
    int co = idx & 15, pos = idx >> 4;
    int j = pos % 6, i = pos / 6;
    float acc = 0.f;
    for (int ky = 0; ky < 3; ++ky)
      for (int kx = 0; kx < 3; ++kx) {
        int base = ((2 * i + ky) * 13 + (2 * j + kx)) * 8;
        int kb = (ky * 3 + kx) * 128 + co;
        #pragma unroll
        for (int ci = 0; ci < 8; ++ci) acc += s_y1[base + ci] * s_k2[kb + ci * 16];
      }
    float v = acc * s_s2[co] + s_b2[co];
    s_y2[idx] = v > 0.f ? v : 0.f;
  }
  __syncthreads();
  for (int idx = tid; idx < 128; idx += 128) {
    int co = idx & 31, pos = idx >> 5;
    int j = pos & 1, i = pos >> 1;
    float acc = 0.f;
    for (int ky = 0; ky < 3; ++ky)
      for (int kx = 0; kx < 3; ++kx) {
        int base = ((2 * i + ky) * 6 + (2 * j + kx)) * 16;
        int kb = (ky * 3 + kx) * 512 + co;
        #pragma unroll
        for (int ci = 0; ci < 16; ++ci) acc += s_y2[base + ci] * s_k3[kb + ci * 32];
      }
    float v = acc * s_s3[co] + s_b3[co];
    FEATP[(size_t)n * 128 + idx] = v > 0.f ? v : 0.f;
  }
}

// ---------------- persistent LSTM scan: pure dataflow, paced polls ----------------
// Counters: CZP (96/step), CHT (64), COH (32), CHP (15), CRV (32), COP (16).
// Parity double-buffers: ZP/OH (s&1), HT_t, RVT_t, OUTPRE ((t+1)&1 for AO_t).
__global__ __launch_bounds__(512) void lstm_kernel(
    const int* __restrict__ labels,
    const float* __restrict__ Wo, const float* __restrict__ bo,
    const float* __restrict__ Wp, const float* __restrict__ bp,
    const float* __restrict__ Wf, const float* __restrict__ bf,
    float* __restrict__ ws, float* __restrict__ out) {
  extern __shared__ float dyn[];
  const float* FEATP = ws + OFF_FEATP;
  const float* WXI   = ws + OFF_WXI;
  const float* WHI   = ws + OFF_WHI;
  const float* BLI   = ws + OFF_BLI;
  float* ZP0    = ws + OFF_ZP0;     // [2][32][2048]
  float* ZP1    = ws + OFF_ZP1;
  float* OH0    = ws + OFF_OH0;     // [2][32][512]
  float* OH1    = ws + OFF_OH1;
  float* HP0    = ws + OFF_HP0;
  float* HP1    = ws + OFF_HP1;
  float* OUTPRE = ws + OFF_OUTPRE;  // [2][32][512]
  float* HT     = ws + OFF_HT;      // [2][512][32]
  float* RVT    = ws + OFF_RVT;     // [2][256][32]
  int*   BARp   = (int*)(ws + OFF_BAR);

  const int bid = blockIdx.x;
  const int tid = threadIdx.x;

  // paced wait: slp=1 (~27ns) for critical arcs, larger for slack roles
  auto waitC = [&](int base, int target, int slp) {
    if (tid == 0) {
      while (sum8_bar(BARp + base) < target) {
        sleep_k(slp);
      }
    }
    __syncthreads();
  };
  auto bumpC = [&](int base) {
    asm volatile("s_waitcnt vmcnt(0)" ::: "memory");
    __syncthreads();
    if (tid == 0) atomicAdd(&BARp[base + ((bid & 7) << 6)], 1);
  };

  // stage 8192-float [256][32] coherent buffer into [256][36]-padded LDS tile
  auto stage_act = [&](float* dst, const float* src) {
    double v[8];
    ld8x2_sc((const double*)src + tid, v);
    #pragma unroll
    for (int j = 0; j < 8; ++j) {
      int i = (tid + j * 512) << 1;
      *(double*)&dst[(i >> 5) * 36 + (i & 31)] = v[j];
    }
  };

  // ---- E32: Y[32c][32b] (R6-validated). K mult of 16.
  auto E32 = [&](const float* Wm, const float* Am, int K, float* part, float2& r) {
    const int wv = tid >> 6, l = tid & 63;
    const int ksub = l & 1, cg = (l >> 1) & 3, bg = l >> 3;
    const int Kp = K >> 4;
    const int kb = wv * (K >> 3) + ksub * Kp;
    const float* wp = Wm + (size_t)kb * 32 + cg * 8;
    const float* ap = Am + (size_t)kb * 36 + bg * 4;
    float4 acc[8];
    #pragma unroll
    for (int i = 0; i < 8; ++i) acc[i] = {0.f, 0.f, 0.f, 0.f};
    #pragma unroll 4
    for (int kk = 0; kk < Kp; ++kk) {
      float4 w0 = *(const float4*)(wp + kk * 32);
      float4 w1 = *(const float4*)(wp + kk * 32 + 4);
      float4 a  = *(const float4*)(ap + kk * 36);
      float wl[8];
      *(float4*)&wl[0] = w0; *(float4*)&wl[4] = w1;
      #pragma unroll
      for (int i = 0; i < 8; ++i) {
        acc[i].x = fmaf(wl[i], a.x, acc[i].x);
        acc[i].y = fmaf(wl[i], a.y, acc[i].y);
        acc[i].z = fmaf(wl[i], a.z, acc[i].z);
        acc[i].w = fmaf(wl[i], a.w, acc[i].w);
      }
    }
    #pragma unroll
    for (int i = 0; i < 8; ++i) {
      acc[i].x += __shfl_xor(acc[i].x, 1, 64);
      acc[i].y += __shfl_xor(acc[i].y, 1, 64);
      acc[i].z += __shfl_xor(acc[i].z, 1, 64);
      acc[i].w += __shfl_xor(acc[i].w, 1, 64);
    }
    const int ob = (cg * 8) * 36 + bg * 4;
    if (ksub == 0 && wv < 4) {
      float* pb = part + wv * 1152 + ob;
      #pragma unroll
      for (int i = 0; i < 8; ++i) *(float4*)(pb + i * 36) = acc[i];
    }
    __syncthreads();
    if (ksub == 0 && wv >= 4) {
      float* pb = part + (wv - 4) * 1152 + ob;
      #pragma unroll
      for (int i = 0; i < 8; ++i) {
        float4 t = *(float4*)(pb + i * 36);
        t.x += acc[i].x; t.y += acc[i].y; t.z += acc[i].z; t.w += acc[i].w;
        *(float4*)(pb + i * 36) = t;
      }
    }
    __syncthreads();
    const int c = tid & 31, b2 = (tid >> 5) * 2;
    const int o = c * 36 + b2;
    float2 s0 = *(float2*)(part + o);
    float2 s1 = *(float2*)(part + 1152 + o);
    float2 s2 = *(float2*)(part + 2304 + o);
    float2 s3 = *(float2*)(part + 3456 + o);
    r.x = (s0.x + s1.x) + (s2.x + s3.x);
    r.y = (s0.y + s1.y) + (s2.y + s3.y);
  };

  // ---- E64: Y[64c][32b], K=256, rotated weight slab (R6-validated).
  auto E64 = [&](const float* Wm, const float* Am, float* part, float4& r) {
    const int wv = tid >> 6, l = tid & 63;
    const int ksub = l & 1, cg = (l >> 1) & 7, bg = l >> 4;
    const int kb = wv * 32 + ksub * 16;
    const float* wp0 = Wm + (size_t)kb * 64 + ((cg * 8 + ksub * 4) & 63);
    const float* wp1 = Wm + (size_t)kb * 64 + ((cg * 8 + 4 + ksub * 4) & 63);
    const float* ap = Am + (size_t)kb * 36 + bg * 8;
    float4 acc[8][2];
    #pragma unroll
    for (int i = 0; i < 8; ++i) { acc[i][0] = {0.f,0.f,0.f,0.f}; acc[i][1] = {0.f,0.f,0.f,0.f}; }
    #pragma unroll 2
    for (int kk = 0; kk < 16; ++kk) {
      float4 w0 = *(const float4*)(wp0 + kk * 64);
      float4 w1 = *(const float4*)(wp1 + kk * 64);
      float4 a0 = *(const float4*)(ap + kk * 36);
      float4 a1 = *(const float4*)(ap + kk * 36 + 4);
      float wl[8];
      *(float4*)&wl[0] = w0; *(float4*)&wl[4] = w1;
      #pragma unroll
      for (int i = 0; i < 8; ++i) {
        acc[i][0].x = fmaf(wl[i], a0.x, acc[i][0].x);
        acc[i][0].y = fmaf(wl[i], a0.y, acc[i][0].y);
        acc[i][0].z = fmaf(wl[i], a0.z, acc[i][0].z);
        acc[i][0].w = fmaf(wl[i], a0.w, acc[i][0].w);
        acc[i][1].x = fmaf(wl[i], a1.x, acc[i][1].x);
        acc[i][1].y = fmaf(wl[i], a1.y, acc[i][1].y);
        acc[i][1].z = fmaf(wl[i], a1.z, acc[i][1].z);
        acc[i][1].w = fmaf(wl[i], a1.w, acc[i][1].w);
      }
    }
    #pragma unroll
    for (int i = 0; i < 8; ++i) {
      #pragma unroll
      for (int j = 0; j < 2; ++j) {
        acc[i][j].x += __shfl_xor(acc[i][j].x, 1, 64);
        acc[i][j].y += __shfl_xor(acc[i][j].y, 1, 64);
        acc[i][j].z += __shfl_xor(acc[i][j].z, 1, 64);
        acc[i][j].w += __shfl_xor(acc[i][j].w, 1, 64);
      }
    }
    const int ob = (cg * 8) * 36 + bg * 8;
    if (ksub == 0 && wv < 4) {
      float* pb = part + wv * 2304 + ob;
      #pragma unroll
      for (int i = 0; i < 8; ++i) {
        *(float4*)(pb + i * 36) = acc[i][0];
        *(float4*)(pb + i * 36 + 4) = acc[i][1];
      }
    }
    __syncthreads();
    if (ksub == 0 && wv >= 4) {
      float* pb = part + (wv - 4) * 2304 + ob;
      #pragma unroll
      for (int i = 0; i < 8; ++i) {
        float4 t0 = *(float4*)(pb + i * 36);
        float4 t1 = *(float4*)(pb + i * 36 + 4);
        t0.x += acc[i][0].x; t0.y += acc[i][0].y; t0.z += acc[i][0].z; t0.w += acc[i][0].w;
        t1.x += acc[i][1].x; t1.y += acc[i][1].y; t1.z += acc[i][1].z; t1.w += acc[i][1].w;
        *(float4*)(pb + i * 36) = t0;
        *(float4*)(pb + i * 36 + 4) = t1;
      }
    }
    __syncthreads();
    const int c = tid & 63, b4 = (tid >> 6) * 4;
    const int o = c * 36 + b4;
    float4 s0 = *(float4*)(part + o);
    float4 s1 = *(float4*)(part + 2304 + o);
    float4 s2 = *(float4*)(part + 4608 + o);
    float4 s3 = *(float4*)(part + 6912 + o);
    r.x = (s0.x + s1.x) + (s2.x + s3.x);
    r.y = (s0.y + s1.y) + (s2.y + s3.y);
    r.z = (s0.z + s1.z) + (s2.z + s3.z);
    r.w = (s0.w + s1.w) + (s2.w + s3.w);
  };

  // ---------------- one-time init: weights -> LDS ----------------
  if (bid < 64) {            // AZ
    const int c0 = bid * 32;
    for (int i = tid; i < 8192; i += 512)
      dyn[i] = WXI[(size_t)(153 + (i >> 5)) * 2048 + c0 + (i & 31)];
    for (int i = tid; i < 4096; i += 512)
      dyn[8192 + i] = WXI[(size_t)(i >> 5) * 2048 + c0 + (i & 31)];
    if (tid < 256) dyn[12288 + tid] = 0.f;  // Cst
  } else if (bid < 80) {     // AO
    const int u0 = (bid - 64) * 32;
    for (int i = tid; i < 8192; i += 512)
      dyn[i] = Wo[(size_t)(512 + (i >> 5)) * 512 + u0 + (i & 31)];
    if (tid < 32) dyn[8192 + tid] = bo[u0 + tid];
  } else if (bid < 144) {    // BL
    const int c0 = (bid - 80) * 32;
    for (int i = tid; i < 8192; i += 512)
      dyn[i] = WHI[(size_t)(i >> 5) * 2048 + c0 + (i & 31)];
    if (tid < 32) dyn[8192 + tid] = BLI[c0 + tid];
  } else if (bid < 176) {    // BH (rotated)
    const int c0 = (bid - 144) * 64;
    for (int i = tid; i < 16384; i += 512) {
      int k = i >> 6, c = i & 63;
      int cr = (c + ((k >> 4) & 1) * 4) & 63;
      dyn[k * 64 + cr] = WHI[(size_t)(256 + k) * 2048 + c0 + c];
    }
  } else if (bid < 192) {    // OL
    const int u0 = (bid - 176) * 32;
    for (int i = tid; i < 8192; i += 512)
      dyn[i] = Wo[(size_t)(i >> 5) * 512 + u0 + (i & 31)];
  } else if (bid < 208) {    // OHI
    const int u0 = (bid - 192) * 32;
    for (int i = tid; i < 8192; i += 512)
      dyn[i] = Wo[(size_t)(256 + (i >> 5)) * 512 + u0 + (i & 31)];
  } else if (bid < 218) {    // PL
    const int j0 = (bid - 208) * 32;
    for (int i = tid; i < 8192; i += 512)
      dyn[i] = Wp[(size_t)(i >> 5) * 320 + j0 + (i & 31)];
  } else if (bid < 223) {    // PHI (rotated)
    const int j0 = (bid - 218) * 64;
    for (int i = tid; i < 16384; i += 512) {
      int k = i >> 6, c = i & 63;
      int cr = (c + ((k >> 4) & 1) * 4) & 63;
      dyn[k * 64 + cr] = Wp[(size_t)(256 + k) * 320 + j0 + c];
    }
  } else if (bid < 255) {    // CA
    for (int i = tid; i < 17000; i += 512) dyn[i] = 0.f;       // ring[250][68]
    for (int i = tid; i < 12800; i += 512) dyn[17000 + i] = Wf[i];
    for (int i = tid; i < 320; i += 512) dyn[29800 + i] = bp[i];
    if (tid < 25) dyn[30120 + tid] = bf[tid];
  }
  __syncthreads();

  // ---------------- role bodies (parity-parameterized) ----------------
  // AZ dyn: Wz[0,8192) Wxx[8192,12288) Cst[12288,12544) rvT[12544,21760)
  //         xT[21760,26368) zx[26368,27392) zf[27392,28416) part[28416,33024)
  auto azGates = [&](int t) {
    const int c0 = bid * 32;
    const float* rvS  = RVT + ((t + 1) & 1) * 8192;   // RVT_{t-1}
    const float* zp0S = ZP0 + (t & 1) * 65536;        // ZP_t
    const float* zp1S = ZP1 + (t & 1) * 65536;
    float* htD = HT + (t & 1) * 16384;                // HT_t
    float* Wz = dyn; float* Cst = dyn + 12288; float* rvT = dyn + 12544;
    float* zx = dyn + 26368; float* zf = dyn + 27392; float* part = dyn + 28416;
    {
      const int b = tid >> 4, c2 = tid & 15;
      double v[10];
      ld10x2_sc((const double*)rvS + tid,
                (const double*)(zp0S + (size_t)b * 2048 + c0) + c2,
                (const double*)(zp1S + (size_t)b * 2048 + c0) + c2, v);
      #pragma unroll
      for (int j = 0; j < 8; ++j) {
        int i = (tid + j * 512) << 1;
        *(double*)&rvT[(i >> 5) * 36 + (i & 31)] = v[j];
      }
      float2 f0 = *(float2*)&v[8], f1 = *(float2*)&v[9];
      float2 s = {f0.x + f1.x, f0.y + f1.y};
      *(double*)&zf[b * 32 + c2 * 2] = *(double*)&s;
    }
    __syncthreads();
    float2 r;
    E32(Wz, rvT, 256, part, r);
    const int c = tid & 31, b2 = (tid >> 5) * 2;
    zf[b2 * 32 + c] += r.x + zx[b2 * 32 + c];
    zf[(b2 + 1) * 32 + c] += r.y + zx[(b2 + 1) * 32 + c];
    __syncthreads();
    if (tid < 256) {
      int u = tid & 7, b = tid >> 3;
      float4 z = *(float4*)(zf + b * 32 + u * 4);
      float ig = sigm(z.x), fg = sigm(z.y), gg = tanhf(z.z), og = sigm(z.w);
      float cc = fg * Cst[b * 8 + u] + ig * gg;
      Cst[b * 8 + u] = cc;
      st_sc(&htD[(size_t)(bid * 8 + u) * 32 + b], og * tanhf(cc));
    }
  };
  auto azX = [&](int tt) {    // zx = x_{tt}@Wx, local
    float* Wxx = dyn + 8192; float* xT = dyn + 21760;
    float* zx = dyn + 26368; float* part = dyn + 28416;
    for (int i = tid; i < 4096; i += 512) {
      int b = i >> 7, k = i & 127;
      xT[k * 36 + b] = FEATP[((size_t)b * 250 + tt) * 128 + k];
    }
    __syncthreads();
    float2 r;
    E32(Wxx, xT, 128, part, r);
    const int c = tid & 31, b2 = (tid >> 5) * 2;
    zx[b2 * 32 + c] = r.x;
    zx[(b2 + 1) * 32 + c] = r.y;
  };
  // AO dyn: W[0,8192) bo[8192,8224) rvT[8224,17440) of[17440,18464) part[18464,23072)
  auto aoOut = [&](int t) {   // outpre_{t-1}: RVT_{t-1}, OH_{t-1} -> OUTPRE[(t+1)&1]
    const int u0 = (bid - 64) * 32;
    const float* rvS  = RVT + ((t + 1) & 1) * 8192;
    const float* oh0S = OH0 + ((t + 1) & 1) * 16384;
    const float* oh1S = OH1 + ((t + 1) & 1) * 16384;
    float* opD = OUTPRE + ((t + 1) & 1) * 16384;
    float* W = dyn; float* bo_l = dyn + 8192; float* rvT = dyn + 8224;
    float* of = dyn + 17440; float* part = dyn + 18464;
    {
      const int b = tid >> 4, c2 = tid & 15;
      double v[10];
      ld10x2_sc((const double*)rvS + tid,
                (const double*)(oh0S + b * 512 + u0) + c2,
                (const double*)(oh1S + b * 512 + u0) + c2, v);
      #pragma unroll
      for (int j = 0; j < 8; ++j) {
        int i = (tid + j * 512) << 1;
        *(double*)&rvT[(i >> 5) * 36 + (i & 31)] = v[j];
      }
      float2 f0 = *(float2*)&v[8], f1 = *(float2*)&v[9];
      float2 s = {f0.x + f1.x, f0.y + f1.y};
      *(double*)&of[b * 32 + c2 * 2] = *(double*)&s;
    }
    __syncthreads();
    float2 r;
    E32(W, rvT, 256, part, r);
    const int c = tid & 31, b2 = (tid >> 5) * 2;
    float bv = bo_l[c];
    st_sc(&opD[b2 * 512 + u0 + c], r.x + of[b2 * 32 + c] + bv);
    st_sc(&opD[(b2 + 1) * 512 + u0 + c], r.y + of[(b2 + 1) * 32 + c] + bv);
  };
  // BL dyn: W[0,8192) blc[8192,8224) slab[8224,8256) A[8256,17472) part[17472,22080)
  auto blLoadLab = [&](int tt1) {
    __syncthreads();
    int* slab = (int*)(dyn + 8224);
    if (tid < 32) slab[tid] = labels[tid * 250 + tt1];
  };
  auto blGemm = [&](int s) {  // produce ZP_s from HT_{s-1}
    const int c0 = (bid - 80) * 32;
    const float* htS = HT + ((s + 1) & 1) * 16384;
    float* zpD = ZP0 + (s & 1) * 65536;
    float* W = dyn; float* blc = dyn + 8192; int* slab = (int*)(dyn + 8224);
    float* A = dyn + 8256; float* part = dyn + 17472;
    stage_act(A, htS);
    __syncthreads();
    float2 r;
    E32(W, A, 256, part, r);
    const int c = tid & 31, b2 = (tid >> 5) * 2;
    float base = blc[c];
    int l0 = slab[b2], l1 = slab[b2 + 1];
    st_sc(&zpD[(size_t)b2 * 2048 + c0 + c],
          r.x + base + WXI[(size_t)(128 + l0) * 2048 + c0 + c]);
    st_sc(&zpD[(size_t)(b2 + 1) * 2048 + c0 + c],
          r.y + base + WXI[(size_t)(128 + l1) * 2048 + c0 + c]);
  };
  // BH dyn: W[0,16384) A[16384,25600) part[25600,34816)
  auto bhGemm = [&](int s) {
    const int c0 = (bid - 144) * 64;
    const float* htS = HT + ((s + 1) & 1) * 16384 + 8192;
    float* zpD = ZP1 + (s & 1) * 65536;
    float* W = dyn; float* A = dyn + 16384; float* part = dyn + 25600;
    stage_act(A, htS);
    __syncthreads();
    float4 r;
    E64(W, A, part, r);
    const int c = tid & 63, b4 = (tid >> 6) * 4;
    st_sc(&zpD[(size_t)(b4 + 0) * 2048 + c0 + c], r.x);
    st_sc(&zpD[(size_t)(b4 + 1) * 2048 + c0 + c], r.y);
    st_sc(&zpD[(size_t)(b4 + 2) * 2048 + c0 + c], r.z);
    st_sc(&zpD[(size_t)(b4 + 3) * 2048 + c0 + c], r.w);
  };
  // OL/OHI/PL: E32; PHI: E64
  auto p2Gemm = [&](int t) {
    const float* htBase = HT + (t & 1) * 16384;
    if (bid < 218) {
      float* W = dyn; float* A = dyn + 8192; float* part = dyn + 17408;
      const bool isOLr = bid < 192, isOHIr = (bid >= 192 && bid < 208);
      stage_act(A, isOHIr ? (htBase + 8192) : htBase);
      __syncthreads();
      float2 r;
      E32(W, A, 256, part, r);
      const int c = tid & 31, b2 = (tid >> 5) * 2;
      if (isOLr) {
        const int u0 = (bid - 176) * 32;
        float* d = OH0 + (t & 1) * 16384;
        st_sc(&d[b2 * 512 + u0 + c], r.x);
        st_sc(&d[(b2 + 1) * 512 + u0 + c], r.y);
      } else if (isOHIr) {
        const int u0 = (bid - 192) * 32;
        float* d = OH1 + (t & 1) * 16384;
        st_sc(&d[b2 * 512 + u0 + c], r.x);
        st_sc(&d[(b2 + 1) * 512 + u0 + c], r.y);
      } else {
        const int j0 = (bid - 208) * 32;
        st_sc(&HP0[b2 * 320 + j0 + c], r.x);
        st_sc(&HP0[(b2 + 1) * 320 + j0 + c], r.y);
      }
    } else {
      const int j0 = (bid - 218) * 64;
      float* W = dyn; float* A = dyn + 16384; float* part = dyn + 25600;
      stage_act(A, htBase + 8192);
      __syncthreads();
      float4 r;
      E64(W, A, part, r);
      const int c = tid & 63, b4 = (tid >> 6) * 4;
      st_sc(&HP1[(b4 + 0) * 320 + j0 + c], r.x);
      st_sc(&HP1[(b4 + 1) * 320 + j0 + c], r.y);
      st_sc(&HP1[(b4 + 2) * 320 + j0 + c], r.z);
      st_sc(&HP1[(b4 + 3) * 320 + j0 + c], r.w);
    }
  };
  // CA dyn: ring[0,17000) Wf[17000,29800) bp[29800,30120) bf[30120,30152)
  //         hid[30152,30472) kn[30472,30728) att4[30728,31752) red[31752,31784)
  //         msum[31784,31800) rvp[31800,33848)  (to/lp/lg alias rvp)
  auto caOut = [&](int t) {
    const float* opS = OUTPRE + ((t + 1) & 1) * 16384;
    float* WfL = dyn + 17000; float* bfL = dyn + 30120;
    float* to  = dyn + 31800; float* lp = dyn + 32312; float* lg = dyn + 32712;
    const int b = bid - 223;
    to[tid] = tanhf(ld_sc(&opS[b * 512 + tid]));
    __syncthreads();
    if (tid < 400) {
      int l = tid % 25, p = tid / 25;
      float s = 0.f;
      #pragma unroll
      for (int q = 0; q < 32; ++q) { int k = p * 32 + q; s += to[k] * WfL[k * 25 + l]; }
      lp[p * 25 + l] = s;
    }
    __syncthreads();
    if (tid < 25) {
      float s = bfL[tid];
      #pragma unroll
      for (int p = 0; p < 16; ++p) s += lp[p * 25 + tid];
      lg[tid] = s;
    }
    __syncthreads();
    if (tid == 0) {
      float mx = lg[0];
      for (int l = 1; l < 25; ++l) mx = fmaxf(mx, lg[l]);
      float ss = 0.f;
      for (int l = 0; l < 25; ++l) ss += __expf(lg[l] - mx);
      lg[25] = mx; lg[26] = 1.f / ss;
    }
    __syncthreads();
    if (tid < 25)
      out[((size_t)b * 250 + (t - 1)) * 25 + tid] = __expf(lg[tid] - lg[25]) * lg[26];
    __syncthreads();
  };
  auto caAtt = [&](int t) {
    float* ring = dyn;
    float* bpL  = dyn + 29800;
    float* hid  = dyn + 30152;
    float* kn   = dyn + 30472;
    float* att4 = dyn + 30728;
    float* red  = dyn + 31752;
    float* msum = dyn + 31784;
    float* rvp  = dyn + 31800;
    const int b = bid - 223;
    float* rvD = RVT + (t & 1) * 8192;
    if (tid < 320) {
      float x, y;
      ldpair_sc(&HP0[b * 320 + tid], &HP1[b * 320 + tid], x, y);
      hid[tid] = tanhf(x + y + bpL[tid]);
    }
    __syncthreads();
    if (tid < 256) {
      float v = hid[64 + tid]; float pq = v * v;
      for (int off = 32; off; off >>= 1) pq += __shfl_down(pq, off, 64);
      if ((tid & 63) == 0) red[tid >> 6] = rsqrtf(fmaxf(pq, 1e-12f));
    }
    __syncthreads();
    if (tid < 256) kn[tid] = hid[64 + tid] * red[tid >> 6];
    __syncthreads();
    const int start = (250 - t) % 250;
    if (tid < 500) {
      int m = tid >> 1, dh = tid & 1;
      int p = start + m; if (p >= 250) p -= 250;
      const float* cell = ring + p * 68;
      const float* k0 = kn + dh * 128;
      float n2 = 0.f, d0 = 0.f, d1 = 0.f;
      #pragma unroll
      for (int s = 0; s < 64; s += 4) {
        float4 q = *(const float4*)(cell + s);
        n2 += q.x * q.x + q.y * q.y + q.z * q.z + q.w * q.w;
        d0 += k0[s] * q.x + k0[s + 1] * q.y + k0[s + 2] * q.z + k0[s + 3] * q.w;
        d1 += k0[64 + s] * q.x + k0[64 + s + 1] * q.y + k0[64 + s + 2] * q.z + k0[64 + s + 3] * q.w;
      }
      float rs = rsqrtf(fmaxf(n2, 1e-12f));
      att4[(2 * dh) * 256 + m] = d0 * rs;
      att4[(2 * dh + 1) * 256 + m] = d1 * rs;
    }
    __syncthreads();
    {
      int h4 = tid >> 7, mm = tid & 127;
      float v0 = att4[h4 * 256 + mm];
      bool has2 = (mm + 128) < 250;
      float v1 = has2 ? att4[h4 * 256 + mm + 128] : -3.0e38f;
      float mx = fmaxf(v0, v1);
      for (int off = 32; off; off >>= 1) mx = fmaxf(mx, __shfl_down(mx, off, 64));
      if ((tid & 63) == 0) red[tid >> 6] = mx;
      __syncthreads();
      float MX = fmaxf(red[h4 * 2], red[h4 * 2 + 1]);
      float e0 = __expf(v0 - MX);
      float e1 = has2 ? __expf(v1 - MX) : 0.f;
      att4[h4 * 256 + mm] = e0;
      if (has2) att4[h4 * 256 + mm + 128] = e1;
      float sm_ = e0 + e1;
      for (int off = 32; off; off >>= 1) sm_ += __shfl_down(sm_, off, 64);
      if ((tid & 63) == 0) red[8 + (tid >> 6)] = sm_;
      __syncthreads();
      if (tid < 4) msum[tid] = red[8 + tid * 2] + red[8 + tid * 2 + 1];
      __syncthreads();
    }
    {
      int h4 = tid >> 7, mh = (tid >> 4) & 7, s4 = tid & 15;
      float4 a = {0.f, 0.f, 0.f, 0.f};
      for (int m = mh; m < 250; m += 8) {
        int p = start + m; if (p >= 250) p -= 250;
        float w = att4[h4 * 256 + m];
        float4 q = *(const float4*)(ring + p * 68 + s4 * 4);
        a.x = fmaf(w, q.x, a.x); a.y = fmaf(w, q.y, a.y);
        a.z = fmaf(w, q.z, a.z); a.w = fmaf(w, q.w, a.w);
      }
      *(float4*)(rvp + tid * 4) = a;
    }
    __syncthreads();
    if (tid < 256) {
      int h = tid >> 6, s = tid & 63;
      float sum = 0.f;
      #pragma unroll
      for (int j = 0; j < 8; ++j)
        sum += rvp[(h * 128 + j * 16 + (s >> 2)) * 4 + (s & 3)];
      st_sc(&rvD[(h * 64 + s) * 32 + b], sum / msum[h]);
    }
    __syncthreads();
    if (tid < 64) {
      int ip = start + 249; if (ip >= 250) ip -= 250;
      ring[ip * 68 + tid] = hid[tid];
    }
  };

  // ---------------- dataflow role loops (paced polls) ----------------
  if (bid < 64) {                       // AZ
    azX(0);
    for (int t = 0; t < 250; ++t) {
      waitC(CZP, 96 * (t + 1), 4);
      if (t >= 1) waitC(CRV, 32 * t, 1);        // critical arc
      if (t >= 2) waitC(COH, 32 * (t - 1), 2);  // HT WAR
      azGates(t);
      bumpC(CHT);
      if (t < 249) azX(t + 1);
    }
  } else if (bid < 80) {                // AO (slack role)
    for (int t = 1; t <= 250; ++t) {
      waitC(CRV, 32 * t, 4);
      waitC(COH, 32 * t, 4);
      aoOut(t);
      bumpC(COP);
    }
  } else if (bid < 144) {               // BL (slack role)
    blLoadLab(0);
    blGemm(0);
    bumpC(CZP);
    for (int t = 0; t <= 248; ++t) {
      blLoadLab(t + 1);
      waitC(CHT, 64 * (t + 1), 8);
      blGemm(t + 1);
      bumpC(CZP);
    }
  } else if (bid < 176) {               // BH (slack role)
    bhGemm(0);
    bumpC(CZP);
    for (int t = 0; t <= 248; ++t) {
      waitC(CHT, 64 * (t + 1), 8);
      bhGemm(t + 1);
      bumpC(CZP);
    }
  } else if (bid < 223) {               // OL/OHI (OH_t) and PL/PHI (HP_t)
    const bool isOH = bid < 208 && bid >= 176;
    for (int t = 0; t < 250; ++t) {
      if (isOH) {
        waitC(CHT, 64 * (t + 1), 2);
        if (t >= 2) waitC(COP, 16 * (t - 1), 2);   // OH WAR
        p2Gemm(t);
        bumpC(COH);
      } else {
        waitC(CHT, 64 * (t + 1), 1);               // critical arc
        if (t >= 1) waitC(CRV, 32 * t, 1);         // HP WAR
        p2Gemm(t);
        bumpC(CHP);
      }
    }
  } else if (bid < 255) {               // CA: attention first (critical), out in slack
    for (int t = 0; t < 250; ++t) {
      waitC(CHP, 15 * (t + 1), 1);                 // critical arc
      caAtt(t);
      bumpC(CRV);
      if (t >= 1) { waitC(COP, 16 * t, 2); caOut(t); }
    }
    waitC(COP, 16 * 250, 2);
    caOut(250);
  }
}

extern "C" void kernel_launch(void* const* d_in, const int* in_sizes, int n_in,
                              void* d_out, int out_size, void* d_ws, size_t ws_size,
                              hipStream_t stream) {
  const float* images = (const float*)d_in[0];
  const int* labels = (const int*)d_in[1];
  const float* k1  = (const float*)d_in[2];
  const float* cb1 = (const float*)d_in[3];
  const float* g1  = (const float*)d_in[4];
  const float* be1 = (const float*)d_in[5];
  const float* mm1 = (const float*)d_in[6];
  const float* mv1 = (const float*)d_in[7];
  const float* k2  = (const float*)d_in[8];
  const float* cb2 = (const float*)d_in[9];
  const float* g2  = (const float*)d_in[10];
  const float* be2 = (const float*)d_in[11];
  const float* mm2 = (const float*)d_in[12];
  const float* mv2 = (const float*)d_in[13];
  const float* k3  = (const float*)d_in[14];
  const float* cb3 = (const float*)d_in[15];
  const float* g3  = (const float*)d_in[16];
  const float* be3 = (const float*)d_in[17];
  const float* mm3 = (const float*)d_in[18];
  const float* mv3 = (const float*)d_in[19];
  const float* Wx  = (const float*)d_in[20];
  const float* Wh  = (const float*)d_in[21];
  const float* bl  = (const float*)d_in[22];
  const float* Wp  = (const float*)d_in[23];
  const float* bp  = (const float*)d_in[24];
  const float* Wo  = (const float*)d_in[25];
  const float* bo  = (const float*)d_in[26];
  const float* Wf  = (const float*)d_in[27];
  const float* bf  = (const float*)d_in[28];
  float* ws = (float*)d_ws;

  hipFuncSetAttribute((const void*)lstm_kernel,
                      hipFuncAttributeMaxDynamicSharedMemorySize, DYN_BYTES);

  // zero activation/state/counter region (ws poisoned 0xAA before each call)
  hipMemsetAsync((char*)d_ws + OFF_ZP0 * sizeof(float), 0,
                 (WS_FLOATS - OFF_ZP0) * sizeof(float), stream);
  prep_kernel<<<1024, 256, 0, stream>>>(Wx, Wh, bl, ws);
  conv_kernel<<<8000, 128, 0, stream>>>(images,
      k1, cb1, g1, be1, mm1, mv1,
      k2, cb2, g2, be2, mm2, mv2,
      k3, cb3, g3, be3, mm3, mv3, ws);
  lstm_kernel<<<256, 512, DYN_BYTES, stream>>>(labels, Wo, bo, Wp, bp, Wf, bf, ws,
                                               (float*)d_out);
}

// Round 13
// 5872.788 us; speedup vs baseline: 1.0423x; 1.0423x over previous
//
#include <hip/hip_runtime.h>

// ---------------- problem constants ----------------
// B=32, T=250, FEAT=128, CLASSES=25, UNITS=512, CELL=64, HEADS=4, IN_LSTM=409

// ---------------- scratch layout (floats) ----------------
constexpr size_t OFF_FEATP  = 0;                              // [8000][128]
constexpr size_t OFF_WXI    = OFF_FEATP + (size_t)8000 * 128; // [409][2048] gate-interleaved
constexpr size_t OFF_WHI    = OFF_WXI + (size_t)409 * 2048;   // [512][2048]
constexpr size_t OFF_BLI    = OFF_WHI + (size_t)512 * 2048;   // [2048]
constexpr size_t OFF_ZP0    = OFF_BLI + 2048;                 // [2][32][2048] parity
constexpr size_t OFF_ZP1    = OFF_ZP0 + 131072;               // [2][32][2048]
constexpr size_t OFF_OH0    = OFF_ZP1 + 131072;               // [2][32][512]
constexpr size_t OFF_OH1    = OFF_OH0 + 32768;                // [2][32][512]
constexpr size_t OFF_HP0    = OFF_OH1 + 32768;                // [32][320]
constexpr size_t OFF_HP1    = OFF_HP0 + 10240;                // [32][320]
constexpr size_t OFF_OUTPRE = OFF_HP1 + 10240;                // [32][512]
constexpr size_t OFF_HT     = OFF_OUTPRE + 16384;             // [2][512][32] parity
constexpr size_t OFF_RVT    = OFF_HT + 32768;                 // [2][256][32] parity
constexpr size_t OFF_BAR    = OFF_RVT + 16384;                // counters (4096 ints)
constexpr size_t WS_FLOATS  = OFF_BAR + 4096;

constexpr int DYN_FLOATS = 34816;                 // 136 KB dynamic LDS
constexpr int DYN_BYTES  = DYN_FLOATS * 4;

// counter bases (ints; 8 lines x 64-int stride each)
constexpr int CZP = 0, CHT = 512, COH = 1024, CHP = 1536, CRV = 2048, COP = 2560;

__device__ __forceinline__ float sigm(float x) { return 1.f / (1.f + __expf(-x)); }

// ---- LLC-coherent accesses (bypass L1+L2). Loads batched in asm with the
// waitcnt inside so they cannot be serialized into dependent round-trips.
__device__ __forceinline__ void st_sc(float* p, float v) {
  __hip_atomic_store(p, v, __ATOMIC_RELAXED, __HIP_MEMORY_SCOPE_AGENT);
}
__device__ __forceinline__ float ld_sc(const float* p) {
  return __hip_atomic_load(p, __ATOMIC_RELAXED, __HIP_MEMORY_SCOPE_AGENT);
}
__device__ __forceinline__ void ld8x2_sc(const double* b0, double* v) {
  const double *p0 = b0, *p1 = b0 + 512, *p2 = b0 + 1024, *p3 = b0 + 1536,
               *p4 = b0 + 2048, *p5 = b0 + 2560, *p6 = b0 + 3072, *p7 = b0 + 3584;
  asm volatile(
      "global_load_dwordx2 %0, %8, off sc0 sc1\n\t"
      "global_load_dwordx2 %1, %9, off sc0 sc1\n\t"
      "global_load_dwordx2 %2, %10, off sc0 sc1\n\t"
      "global_load_dwordx2 %3, %11, off sc0 sc1\n\t"
      "global_load_dwordx2 %4, %12, off sc0 sc1\n\t"
      "global_load_dwordx2 %5, %13, off sc0 sc1\n\t"
      "global_load_dwordx2 %6, %14, off sc0 sc1\n\t"
      "global_load_dwordx2 %7, %15, off sc0 sc1\n\t"
      "s_waitcnt vmcnt(0)"
      : "=&v"(v[0]), "=&v"(v[1]), "=&v"(v[2]), "=&v"(v[3]),
        "=&v"(v[4]), "=&v"(v[5]), "=&v"(v[6]), "=&v"(v[7])
      : "v"(p0), "v"(p1), "v"(p2), "v"(p3), "v"(p4), "v"(p5), "v"(p6), "v"(p7)
      : "memory");
}
// 8 rv loads + 2 partial loads, one waitcnt (gates/outpre staging)
__device__ __forceinline__ void ld10x2_sc(const double* b0, const double* z0,
                                          const double* z1, double* v) {
  const double *p0 = b0, *p1 = b0 + 512, *p2 = b0 + 1024, *p3 = b0 + 1536,
               *p4 = b0 + 2048, *p5 = b0 + 2560, *p6 = b0 + 3072, *p7 = b0 + 3584;
  asm volatile(
      "global_load_dwordx2 %0, %10, off sc0 sc1\n\t"
      "global_load_dwordx2 %1, %11, off sc0 sc1\n\t"
      "global_load_dwordx2 %2, %12, off sc0 sc1\n\t"
      "global_load_dwordx2 %3, %13, off sc0 sc1\n\t"
      "global_load_dwordx2 %4, %14, off sc0 sc1\n\t"
      "global_load_dwordx2 %5, %15, off sc0 sc1\n\t"
      "global_load_dwordx2 %6, %16, off sc0 sc1\n\t"
      "global_load_dwordx2 %7, %17, off sc0 sc1\n\t"
      "global_load_dwordx2 %8, %18, off sc0 sc1\n\t"
      "global_load_dwordx2 %9, %19, off sc0 sc1\n\t"
      "s_waitcnt vmcnt(0)"
      : "=&v"(v[0]), "=&v"(v[1]), "=&v"(v[2]), "=&v"(v[3]), "=&v"(v[4]),
        "=&v"(v[5]), "=&v"(v[6]), "=&v"(v[7]), "=&v"(v[8]), "=&v"(v[9])
      : "v"(p0), "v"(p1), "v"(p2), "v"(p3), "v"(p4), "v"(p5), "v"(p6), "v"(p7),
        "v"(z0), "v"(z1)
      : "memory");
}
__device__ __forceinline__ void ldpair_sc(const float* a, const float* b,
                                          float& x, float& y) {
  asm volatile(
      "global_load_dword %0, %2, off sc0 sc1\n\t"
      "global_load_dword %1, %3, off sc0 sc1\n\t"
      "s_waitcnt vmcnt(0)"
      : "=&v"(x), "=&v"(y) : "v"(a), "v"(b) : "memory");
}
// counter poll: sum of 8 lines, single batched round trip
__device__ __forceinline__ int sum8_bar(const int* b) {
  int v0, v1, v2, v3, v4, v5, v6, v7;
  asm volatile(
      "global_load_dword %0, %8, off sc0 sc1\n\t"
      "global_load_dword %1, %9, off sc0 sc1\n\t"
      "global_load_dword %2, %10, off sc0 sc1\n\t"
      "global_load_dword %3, %11, off sc0 sc1\n\t"
      "global_load_dword %4, %12, off sc0 sc1\n\t"
      "global_load_dword %5, %13, off sc0 sc1\n\t"
      "global_load_dword %6, %14, off sc0 sc1\n\t"
      "global_load_dword %7, %15, off sc0 sc1\n\t"
      "s_waitcnt vmcnt(0)"
      : "=&v"(v0), "=&v"(v1), "=&v"(v2), "=&v"(v3),
        "=&v"(v4), "=&v"(v5), "=&v"(v6), "=&v"(v7)
      : "v"(b), "v"(b + 64), "v"(b + 128), "v"(b + 192),
        "v"(b + 256), "v"(b + 320), "v"(b + 384), "v"(b + 448)
      : "memory");
  return ((v0 + v1) + (v2 + v3)) + ((v4 + v5) + (v6 + v7));
}

// ---------------- weight re-layout: gate-interleaved Wx/Wh/bl ----------------
__global__ __launch_bounds__(256) void prep_kernel(const float* __restrict__ Wx,
                                                   const float* __restrict__ Wh,
                                                   const float* __restrict__ bl,
                                                   float* __restrict__ ws) {
  float* WXI = ws + OFF_WXI;
  float* WHI = ws + OFF_WHI;
  float* BLI = ws + OFF_BLI;
  const int total = 409 * 2048 + 512 * 2048 + 2048;
  for (int idx = blockIdx.x * blockDim.x + threadIdx.x; idx < total;
       idx += gridDim.x * blockDim.x) {
    if (idx < 409 * 2048) {
      int k = idx >> 11, cc = idx & 2047;
      WXI[idx] = Wx[(size_t)k * 2048 + (cc & 3) * 512 + (cc >> 2)];
    } else if (idx < 409 * 2048 + 512 * 2048) {
      int j = idx - 409 * 2048;
      int k = j >> 11, cc = j & 2047;
      WHI[j] = Wh[(size_t)k * 2048 + (cc & 3) * 512 + (cc >> 2)];
    } else {
      int cc = idx - (409 * 2048 + 512 * 2048);
      BLI[cc] = bl[(cc & 3) * 512 + (cc >> 2)];
    }
  }
}

// ---------------- conv stack (validated) ----------------
__global__ __launch_bounds__(128) void conv_kernel(
    const float* __restrict__ img,
    const float* __restrict__ k1, const float* __restrict__ cb1, const float* __restrict__ g1,
    const float* __restrict__ be1, const float* __restrict__ mm1, const float* __restrict__ mv1,
    const float* __restrict__ k2, const float* __restrict__ cb2, const float* __restrict__ g2,
    const float* __restrict__ be2, const float* __restrict__ mm2, const float* __restrict__ mv2,
    const float* __restrict__ k3, const float* __restrict__ cb3, const float* __restrict__ g3,
    const float* __restrict__ be3, const float* __restrict__ mm3, const float* __restrict__ mv3,
    float* __restrict__ ws) {
  __shared__ float s_in[784];
  __shared__ float s_y1[13 * 13 * 8];
  __shared__ float s_y2[6 * 6 * 16];
  __shared__ float s_k1[72], s_k2[1152], s_k3[4608];
  __shared__ float s_s1[8], s_b1[8], s_s2[16], s_b2[16], s_s3[32], s_b3[32];
  float* FEATP = ws + OFF_FEATP;
  const int n = blockIdx.x, tid = threadIdx.x;
  const float* ip = img + (size_t)n * 784;
  for (int i = tid; i < 784; i += 128) s_in[i] = ip[i];
  for (int i = tid; i < 72; i += 128) s_k1[i] = k1[i];
  for (int i = tid; i < 1152; i += 128) s_k2[i] = k2[i];
  for (int i = tid; i < 4608; i += 128) s_k3[i] = k3[i];
  if (tid < 8) {
    float s = g1[tid] * rsqrtf(mv1[tid] + 1e-3f);
    s_s1[tid] = s; s_b1[tid] = (cb1[tid] - mm1[tid]) * s + be1[tid];
  } else if (tid >= 32 && tid < 48) {
    int c = tid - 32;
    float s = g2[c] * rsqrtf(mv2[c] + 1e-3f);
    s_s2[c] = s; s_b2[c] = (cb2[c] - mm2[c]) * s + be2[c];
  } else if (tid >= 64 && tid < 96) {
    int c = tid - 64;
    float s = g3[c] * rsqrtf(mv3[c] + 1e-3f);
    s_s3[c] = s; s_b3[c] = (cb3[c] - mm3[c]) * s + be3[c];
  }
  __syncthreads();
  for (int idx = tid; idx < 13 * 13 * 8; idx += 128) {
    int co = idx & 7, pos = idx >> 3;
    int j = pos % 13, i = pos / 13;
    float acc = 0.f;
    #pragma unroll
    for (int ky = 0; ky < 3; ++ky)
      #pragma unroll
      for (int kx = 0; kx < 3; ++kx)
        acc += s_in[(2 * i + ky) * 28 + (2 * j + kx)] * s_k1[(ky * 3 + kx) * 8 + co];
    float v = acc * s_s1[co] + s_b1[co];
    s_y1[idx] = v > 0.f ? v : 0.f;
  }
  __syncthreads();
  for (int idx = tid; idx < 6 * 6 * 16; idx += 128) {
    int co = idx & 15, pos = idx >> 4;
    int j = pos % 6, i = pos / 6;
    float acc = 0.f;
    for (int ky = 0; ky < 3; ++ky)
      for (int kx = 0; kx < 3; ++kx) {
        int base = ((2 * i + ky) * 13 + (2 * j + kx)) * 8;
        int kb = (ky * 3 + kx) * 128 + co;
        #pragma unroll
        for (int ci = 0; ci < 8; ++ci) acc += s_y1[base + ci] * s_k2[kb + ci * 16];
      }
    float v = acc * s_s2[co] + s_b2[co];
    s_y2[idx] = v > 0.f ? v : 0.f;
  }
  __syncthreads();
  for (int idx = tid; idx < 128; idx += 128) {
    int co = idx & 31, pos = idx >> 5;
    int j = pos & 1, i = pos >> 1;
    float acc = 0.f;
    for (int ky = 0; ky < 3; ++ky)
      for (int kx = 0; kx < 3; ++kx) {
        int base = ((2 * i + ky) * 6 + (2 * j + kx)) * 16;
        int kb = (ky * 3 + kx) * 512 + co;
        #pragma unroll
        for (int ci = 0; ci < 16; ++ci) acc += s_y2[base + ci] * s_k3[kb + ci * 32];
      }
    float v = acc * s_s3[co] + s_b3[co];
    FEATP[(size_t)n * 128 + idx] = v > 0.f ? v : 0.f;
  }
}

// ---------------- persistent LSTM scan: pure dataflow, no global barrier ----------------
// Counters: CZP (96/step), CHT (64), COH (32), CHP (15), CRV (32), COP (16).
// Double-buffered by parity: ZP/OH (parity s&1 for product s), HT_t, RVT_t.
__global__ __launch_bounds__(512) void lstm_kernel(
    const int* __restrict__ labels,
    const float* __restrict__ Wo, const float* __restrict__ bo,
    const float* __restrict__ Wp, const float* __restrict__ bp,
    const float* __restrict__ Wf, const float* __restrict__ bf,
    float* __restrict__ ws, float* __restrict__ out) {
  extern __shared__ float dyn[];
  const float* FEATP = ws + OFF_FEATP;
  const float* WXI   = ws + OFF_WXI;
  const float* WHI   = ws + OFF_WHI;
  const float* BLI   = ws + OFF_BLI;
  float* ZP0    = ws + OFF_ZP0;     // [2][32][2048]
  float* ZP1    = ws + OFF_ZP1;
  float* OH0    = ws + OFF_OH0;     // [2][32][512]
  float* OH1    = ws + OFF_OH1;
  float* HP0    = ws + OFF_HP0;
  float* HP1    = ws + OFF_HP1;
  float* OUTPRE = ws + OFF_OUTPRE;
  float* HT     = ws + OFF_HT;      // [2][512][32]
  float* RVT    = ws + OFF_RVT;     // [2][256][32]
  int*   BARp   = (int*)(ws + OFF_BAR);

  const int bid = blockIdx.x;
  const int tid = threadIdx.x;

  auto waitC = [&](int base, int target) {
    if (tid == 0) {
      while (sum8_bar(BARp + base) < target) {}
    }
    __syncthreads();
  };
  auto bumpC = [&](int base) {
    asm volatile("s_waitcnt vmcnt(0)" ::: "memory");
    __syncthreads();
    if (tid == 0) atomicAdd(&BARp[base + ((bid & 7) << 6)], 1);
  };

  // stage 8192-float [256][32] coherent buffer into [256][36]-padded LDS tile
  auto stage_act = [&](float* dst, const float* src) {
    double v[8];
    ld8x2_sc((const double*)src + tid, v);
    #pragma unroll
    for (int j = 0; j < 8; ++j) {
      int i = (tid + j * 512) << 1;
      *(double*)&dst[(i >> 5) * 36 + (i & 31)] = v[j];
    }
  };

  // ---- E32: Y[32c][32b] (R6-validated). K mult of 16.
  auto E32 = [&](const float* Wm, const float* Am, int K, float* part, float2& r) {
    const int wv = tid >> 6, l = tid & 63;
    const int ksub = l & 1, cg = (l >> 1) & 3, bg = l >> 3;
    const int Kp = K >> 4;
    const int kb = wv * (K >> 3) + ksub * Kp;
    const float* wp = Wm + (size_t)kb * 32 + cg * 8;
    const float* ap = Am + (size_t)kb * 36 + bg * 4;
    float4 acc[8];
    #pragma unroll
    for (int i = 0; i < 8; ++i) acc[i] = {0.f, 0.f, 0.f, 0.f};
    #pragma unroll 4
    for (int kk = 0; kk < Kp; ++kk) {
      float4 w0 = *(const float4*)(wp + kk * 32);
      float4 w1 = *(const float4*)(wp + kk * 32 + 4);
      float4 a  = *(const float4*)(ap + kk * 36);
      float wl[8];
      *(float4*)&wl[0] = w0; *(float4*)&wl[4] = w1;
      #pragma unroll
      for (int i = 0; i < 8; ++i) {
        acc[i].x = fmaf(wl[i], a.x, acc[i].x);
        acc[i].y = fmaf(wl[i], a.y, acc[i].y);
        acc[i].z = fmaf(wl[i], a.z, acc[i].z);
        acc[i].w = fmaf(wl[i], a.w, acc[i].w);
      }
    }
    #pragma unroll
    for (int i = 0; i < 8; ++i) {
      acc[i].x += __shfl_xor(acc[i].x, 1, 64);
      acc[i].y += __shfl_xor(acc[i].y, 1, 64);
      acc[i].z += __shfl_xor(acc[i].z, 1, 64);
      acc[i].w += __shfl_xor(acc[i].w, 1, 64);
    }
    const int ob = (cg * 8) * 36 + bg * 4;
    if (ksub == 0 && wv < 4) {
      float* pb = part + wv * 1152 + ob;
      #pragma unroll
      for (int i = 0; i < 8; ++i) *(float4*)(pb + i * 36) = acc[i];
    }
    __syncthreads();
    if (ksub == 0 && wv >= 4) {
      float* pb = part + (wv - 4) * 1152 + ob;
      #pragma unroll
      for (int i = 0; i < 8; ++i) {
        float4 t = *(float4*)(pb + i * 36);
        t.x += acc[i].x; t.y += acc[i].y; t.z += acc[i].z; t.w += acc[i].w;
        *(float4*)(pb + i * 36) = t;
      }
    }
    __syncthreads();
    const int c = tid & 31, b2 = (tid >> 5) * 2;
    const int o = c * 36 + b2;
    float2 s0 = *(float2*)(part + o);
    float2 s1 = *(float2*)(part + 1152 + o);
    float2 s2 = *(float2*)(part + 2304 + o);
    float2 s3 = *(float2*)(part + 3456 + o);
    r.x = (s0.x + s1.x) + (s2.x + s3.x);
    r.y = (s0.y + s1.y) + (s2.y + s3.y);
  };

  // ---- E64: Y[64c][32b], K=256, rotated weight slab (R6-validated).
  auto E64 = [&](const float* Wm, const float* Am, float* part, float4& r) {
    const int wv = tid >> 6, l = tid & 63;
    const int ksub = l & 1, cg = (l >> 1) & 7, bg = l >> 4;
    const int kb = wv * 32 + ksub * 16;
    const float* wp0 = Wm + (size_t)kb * 64 + ((cg * 8 + ksub * 4) & 63);
    const float* wp1 = Wm + (size_t)kb * 64 + ((cg * 8 + 4 + ksub * 4) & 63);
    const float* ap = Am + (size_t)kb * 36 + bg * 8;
    float4 acc[8][2];
    #pragma unroll
    for (int i = 0; i < 8; ++i) { acc[i][0] = {0.f,0.f,0.f,0.f}; acc[i][1] = {0.f,0.f,0.f,0.f}; }
    #pragma unroll 2
    for (int kk = 0; kk < 16; ++kk) {
      float4 w0 = *(const float4*)(wp0 + kk * 64);
      float4 w1 = *(const float4*)(wp1 + kk * 64);
      float4 a0 = *(const float4*)(ap + kk * 36);
      float4 a1 = *(const float4*)(ap + kk * 36 + 4);
      float wl[8];
      *(float4*)&wl[0] = w0; *(float4*)&wl[4] = w1;
      #pragma unroll
      for (int i = 0; i < 8; ++i) {
        acc[i][0].x = fmaf(wl[i], a0.x, acc[i][0].x);
        acc[i][0].y = fmaf(wl[i], a0.y, acc[i][0].y);
        acc[i][0].z = fmaf(wl[i], a0.z, acc[i][0].z);
        acc[i][0].w = fmaf(wl[i], a0.w, acc[i][0].w);
        acc[i][1].x = fmaf(wl[i], a1.x, acc[i][1].x);
        acc[i][1].y = fmaf(wl[i], a1.y, acc[i][1].y);
        acc[i][1].z = fmaf(wl[i], a1.z, acc[i][1].z);
        acc[i][1].w = fmaf(wl[i], a1.w, acc[i][1].w);
      }
    }
    #pragma unroll
    for (int i = 0; i < 8; ++i) {
      #pragma unroll
      for (int j = 0; j < 2; ++j) {
        acc[i][j].x += __shfl_xor(acc[i][j].x, 1, 64);
        acc[i][j].y += __shfl_xor(acc[i][j].y, 1, 64);
        acc[i][j].z += __shfl_xor(acc[i][j].z, 1, 64);
        acc[i][j].w += __shfl_xor(acc[i][j].w, 1, 64);
      }
    }
    const int ob = (cg * 8) * 36 + bg * 8;
    if (ksub == 0 && wv < 4) {
      float* pb = part + wv * 2304 + ob;
      #pragma unroll
      for (int i = 0; i < 8; ++i) {
        *(float4*)(pb + i * 36) = acc[i][0];
        *(float4*)(pb + i * 36 + 4) = acc[i][1];
      }
    }
    __syncthreads();
    if (ksub == 0 && wv >= 4) {
      float* pb = part + (wv - 4) * 2304 + ob;
      #pragma unroll
      for (int i = 0; i < 8; ++i) {
        float4 t0 = *(float4*)(pb + i * 36);
        float4 t1 = *(float4*)(pb + i * 36 + 4);
        t0.x += acc[i][0].x; t0.y += acc[i][0].y; t0.z += acc[i][0].z; t0.w += acc[i][0].w;
        t1.x += acc[i][1].x; t1.y += acc[i][1].y; t1.z += acc[i][1].z; t1.w += acc[i][1].w;
        *(float4*)(pb + i * 36) = t0;
        *(float4*)(pb + i * 36 + 4) = t1;
      }
    }
    __syncthreads();
    const int c = tid & 63, b4 = (tid >> 6) * 4;
    const int o = c * 36 + b4;
    float4 s0 = *(float4*)(part + o);
    float4 s1 = *(float4*)(part + 2304 + o);
    float4 s2 = *(float4*)(part + 4608 + o);
    float4 s3 = *(float4*)(part + 6912 + o);
    r.x = (s0.x + s1.x) + (s2.x + s3.x);
    r.y = (s0.y + s1.y) + (s2.y + s3.y);
    r.z = (s0.z + s1.z) + (s2.z + s3.z);
    r.w = (s0.w + s1.w) + (s2.w + s3.w);
  };

  // ---------------- one-time init: weights -> LDS ----------------
  if (bid < 64) {            // AZ
    const int c0 = bid * 32;
    for (int i = tid; i < 8192; i += 512)
      dyn[i] = WXI[(size_t)(153 + (i >> 5)) * 2048 + c0 + (i & 31)];
    for (int i = tid; i < 4096; i += 512)
      dyn[8192 + i] = WXI[(size_t)(i >> 5) * 2048 + c0 + (i & 31)];
    if (tid < 256) dyn[12288 + tid] = 0.f;  // Cst
  } else if (bid < 80) {     // AO
    const int u0 = (bid - 64) * 32;
    for (int i = tid; i < 8192; i += 512)
      dyn[i] = Wo[(size_t)(512 + (i >> 5)) * 512 + u0 + (i & 31)];
    if (tid < 32) dyn[8192 + tid] = bo[u0 + tid];
  } else if (bid < 144) {    // BL
    const int c0 = (bid - 80) * 32;
    for (int i = tid; i < 8192; i += 512)
      dyn[i] = WHI[(size_t)(i >> 5) * 2048 + c0 + (i & 31)];
    if (tid < 32) dyn[8192 + tid] = BLI[c0 + tid];
  } else if (bid < 176) {    // BH (rotated)
    const int c0 = (bid - 144) * 64;
    for (int i = tid; i < 16384; i += 512) {
      int k = i >> 6, c = i & 63;
      int cr = (c + ((k >> 4) & 1) * 4) & 63;
      dyn[k * 64 + cr] = WHI[(size_t)(256 + k) * 2048 + c0 + c];
    }
  } else if (bid < 192) {    // OL
    const int u0 = (bid - 176) * 32;
    for (int i = tid; i < 8192; i += 512)
      dyn[i] = Wo[(size_t)(i >> 5) * 512 + u0 + (i & 31)];
  } else if (bid < 208) {    // OHI
    const int u0 = (bid - 192) * 32;
    for (int i = tid; i < 8192; i += 512)
      dyn[i] = Wo[(size_t)(256 + (i >> 5)) * 512 + u0 + (i & 31)];
  } else if (bid < 218) {    // PL
    const int j0 = (bid - 208) * 32;
    for (int i = tid; i < 8192; i += 512)
      dyn[i] = Wp[(size_t)(i >> 5) * 320 + j0 + (i & 31)];
  } else if (bid < 223) {    // PHI (rotated)
    const int j0 = (bid - 218) * 64;
    for (int i = tid; i < 16384; i += 512) {
      int k = i >> 6, c = i & 63;
      int cr = (c + ((k >> 4) & 1) * 4) & 63;
      dyn[k * 64 + cr] = Wp[(size_t)(256 + k) * 320 + j0 + c];
    }
  } else if (bid < 255) {    // CA
    for (int i = tid; i < 17000; i += 512) dyn[i] = 0.f;       // ring[250][68]
    for (int i = tid; i < 12800; i += 512) dyn[17000 + i] = Wf[i];
    for (int i = tid; i < 320; i += 512) dyn[29800 + i] = bp[i];
    if (tid < 25) dyn[30120 + tid] = bf[tid];
  }
  __syncthreads();

  // ---------------- role bodies (parity-parameterized) ----------------
  // AZ dyn: Wz[0,8192) Wxx[8192,12288) Cst[12288,12544) rvT[12544,21760)
  //         xT[21760,26368) zx[26368,27392) zf[27392,28416) part[28416,33024)
  auto azGates = [&](int t) {
    const int c0 = bid * 32;
    const float* rvS  = RVT + ((t + 1) & 1) * 8192;   // RVT_{t-1}
    const float* zp0S = ZP0 + (t & 1) * 65536;        // ZP_t
    const float* zp1S = ZP1 + (t & 1) * 65536;
    float* htD = HT + (t & 1) * 16384;                // HT_t
    float* Wz = dyn; float* Cst = dyn + 12288; float* rvT = dyn + 12544;
    float* zx = dyn + 26368; float* zf = dyn + 27392; float* part = dyn + 28416;
    {
      const int b = tid >> 4, c2 = tid & 15;
      double v[10];
      ld10x2_sc((const double*)rvS + tid,
                (const double*)(zp0S + (size_t)b * 2048 + c0) + c2,
                (const double*)(zp1S + (size_t)b * 2048 + c0) + c2, v);
      #pragma unroll
      for (int j = 0; j < 8; ++j) {
        int i = (tid + j * 512) << 1;
        *(double*)&rvT[(i >> 5) * 36 + (i & 31)] = v[j];
      }
      float2 f0 = *(float2*)&v[8], f1 = *(float2*)&v[9];
      float2 s = {f0.x + f1.x, f0.y + f1.y};
      *(double*)&zf[b * 32 + c2 * 2] = *(double*)&s;
    }
    __syncthreads();
    float2 r;
    E32(Wz, rvT, 256, part, r);
    const int c = tid & 31, b2 = (tid >> 5) * 2;
    zf[b2 * 32 + c] += r.x + zx[b2 * 32 + c];
    zf[(b2 + 1) * 32 + c] += r.y + zx[(b2 + 1) * 32 + c];
    __syncthreads();
    if (tid < 256) {
      int u = tid & 7, b = tid >> 3;
      float4 z = *(float4*)(zf + b * 32 + u * 4);
      float ig = sigm(z.x), fg = sigm(z.y), gg = tanhf(z.z), og = sigm(z.w);
      float cc = fg * Cst[b * 8 + u] + ig * gg;
      Cst[b * 8 + u] = cc;
      st_sc(&htD[(size_t)(bid * 8 + u) * 32 + b], og * tanhf(cc));
    }
  };
  auto azX = [&](int tt) {    // zx = x_{tt}@Wx, local
    float* Wxx = dyn + 8192; float* xT = dyn + 21760;
    float* zx = dyn + 26368; float* part = dyn + 28416;
    for (int i = tid; i < 4096; i += 512) {
      int b = i >> 7, k = i & 127;
      xT[k * 36 + b] = FEATP[((size_t)b * 250 + tt) * 128 + k];
    }
    __syncthreads();
    float2 r;
    E32(Wxx, xT, 128, part, r);
    const int c = tid & 31, b2 = (tid >> 5) * 2;
    zx[b2 * 32 + c] = r.x;
    zx[(b2 + 1) * 32 + c] = r.y;
  };
  // AO dyn: W[0,8192) bo[8192,8224) rvT[8224,17440) of[17440,18464) part[18464,23072)
  auto aoOut = [&](int t) {   // outpre_{t-1}: RVT_{t-1}, OH_{t-1}
    const int u0 = (bid - 64) * 32;
    const float* rvS  = RVT + ((t + 1) & 1) * 8192;
    const float* oh0S = OH0 + ((t + 1) & 1) * 16384;
    const float* oh1S = OH1 + ((t + 1) & 1) * 16384;
    float* W = dyn; float* bo_l = dyn + 8192; float* rvT = dyn + 8224;
    float* of = dyn + 17440; float* part = dyn + 18464;
    {
      const int b = tid >> 4, c2 = tid & 15;
      double v[10];
      ld10x2_sc((const double*)rvS + tid,
                (const double*)(oh0S + b * 512 + u0) + c2,
                (const double*)(oh1S + b * 512 + u0) + c2, v);
      #pragma unroll
      for (int j = 0; j < 8; ++j) {
        int i = (tid + j * 512) << 1;
        *(double*)&rvT[(i >> 5) * 36 + (i & 31)] = v[j];
      }
      float2 f0 = *(float2*)&v[8], f1 = *(float2*)&v[9];
      float2 s = {f0.x + f1.x, f0.y + f1.y};
      *(double*)&of[b * 32 + c2 * 2] = *(double*)&s;
    }
    __syncthreads();
    float2 r;
    E32(W, rvT, 256, part, r);
    const int c = tid & 31, b2 = (tid >> 5) * 2;
    float bv = bo_l[c];
    st_sc(&OUTPRE[b2 * 512 + u0 + c], r.x + of[b2 * 32 + c] + bv);
    st_sc(&OUTPRE[(b2 + 1) * 512 + u0 + c], r.y + of[(b2 + 1) * 32 + c] + bv);
  };
  // BL dyn: W[0,8192) blc[8192,8224) slab[8224,8256) A[8256,17472) part[17472,22080)
  auto blLoadLab = [&](int tt1) {
    __syncthreads();
    int* slab = (int*)(dyn + 8224);
    if (tid < 32) slab[tid] = labels[tid * 250 + tt1];
  };
  auto blGemm = [&](int s) {  // produce ZP_s from HT_{s-1}
    const int c0 = (bid - 80) * 32;
    const float* htS = HT + ((s + 1) & 1) * 16384;
    float* zpD = ZP0 + (s & 1) * 65536;
    float* W = dyn; float* blc = dyn + 8192; int* slab = (int*)(dyn + 8224);
    float* A = dyn + 8256; float* part = dyn + 17472;
    stage_act(A, htS);
    __syncthreads();
    float2 r;
    E32(W, A, 256, part, r);
    const int c = tid & 31, b2 = (tid >> 5) * 2;
    float base = blc[c];
    int l0 = slab[b2], l1 = slab[b2 + 1];
    st_sc(&zpD[(size_t)b2 * 2048 + c0 + c],
          r.x + base + WXI[(size_t)(128 + l0) * 2048 + c0 + c]);
    st_sc(&zpD[(size_t)(b2 + 1) * 2048 + c0 + c],
          r.y + base + WXI[(size_t)(128 + l1) * 2048 + c0 + c]);
  };
  // BH dyn: W[0,16384) A[16384,25600) part[25600,34816)
  auto bhGemm = [&](int s) {
    const int c0 = (bid - 144) * 64;
    const float* htS = HT + ((s + 1) & 1) * 16384 + 8192;
    float* zpD = ZP1 + (s & 1) * 65536;
    float* W = dyn; float* A = dyn + 16384; float* part = dyn + 25600;
    stage_act(A, htS);
    __syncthreads();
    float4 r;
    E64(W, A, part, r);
    const int c = tid & 63, b4 = (tid >> 6) * 4;
    st_sc(&zpD[(size_t)(b4 + 0) * 2048 + c0 + c], r.x);
    st_sc(&zpD[(size_t)(b4 + 1) * 2048 + c0 + c], r.y);
    st_sc(&zpD[(size_t)(b4 + 2) * 2048 + c0 + c], r.z);
    st_sc(&zpD[(size_t)(b4 + 3) * 2048 + c0 + c], r.w);
  };
  // OL/OHI/PL: E32; PHI: E64 (producers of OH_t / HP_t)
  auto p2Gemm = [&](int t) {
    const float* htBase = HT + (t & 1) * 16384;
    if (bid < 218) {
      float* W = dyn; float* A = dyn + 8192; float* part = dyn + 17408;
      const bool isOLr = bid < 192, isOHIr = (bid >= 192 && bid < 208);
      stage_act(A, isOHIr ? (htBase + 8192) : htBase);
      __syncthreads();
      float2 r;
      E32(W, A, 256, part, r);
      const int c = tid & 31, b2 = (tid >> 5) * 2;
      if (isOLr) {
        const int u0 = (bid - 176) * 32;
        float* d = OH0 + (t & 1) * 16384;
        st_sc(&d[b2 * 512 + u0 + c], r.x);
        st_sc(&d[(b2 + 1) * 512 + u0 + c], r.y);
      } else if (isOHIr) {
        const int u0 = (bid - 192) * 32;
        float* d = OH1 + (t & 1) * 16384;
        st_sc(&d[b2 * 512 + u0 + c], r.x);
        st_sc(&d[(b2 + 1) * 512 + u0 + c], r.y);
      } else {
        const int j0 = (bid - 208) * 32;
        st_sc(&HP0[b2 * 320 + j0 + c], r.x);
        st_sc(&HP0[(b2 + 1) * 320 + j0 + c], r.y);
      }
    } else {
      const int j0 = (bid - 218) * 64;
      float* W = dyn; float* A = dyn + 16384; float* part = dyn + 25600;
      stage_act(A, htBase + 8192);
      __syncthreads();
      float4 r;
      E64(W, A, part, r);
      const int c = tid & 63, b4 = (tid >> 6) * 4;
      st_sc(&HP1[(b4 + 0) * 320 + j0 + c], r.x);
      st_sc(&HP1[(b4 + 1) * 320 + j0 + c], r.y);
      st_sc(&HP1[(b4 + 2) * 320 + j0 + c], r.z);
      st_sc(&HP1[(b4 + 3) * 320 + j0 + c], r.w);
    }
  };
  // CA dyn: ring[0,17000) Wf[17000,29800) bp[29800,30120) bf[30120,30152)
  //         hid[30152,30472) kn[30472,30728) att4[30728,31752) red[31752,31784)
  //         msum[31784,31800) rvp[31800,33848)  (to/lp/lg alias rvp)
  auto caOut = [&](int t) {
    float* WfL = dyn + 17000; float* bfL = dyn + 30120;
    float* to  = dyn + 31800; float* lp = dyn + 32312; float* lg = dyn + 32712;
    const int b = bid - 223;
    to[tid] = tanhf(ld_sc(&OUTPRE[b * 512 + tid]));
    __syncthreads();
    if (tid < 400) {
      int l = tid % 25, p = tid / 25;
      float s = 0.f;
      #pragma unroll
      for (int q = 0; q < 32; ++q) { int k = p * 32 + q; s += to[k] * WfL[k * 25 + l]; }
      lp[p * 25 + l] = s;
    }
    __syncthreads();
    if (tid < 25) {
      float s = bfL[tid];
      #pragma unroll
      for (int p = 0; p < 16; ++p) s += lp[p * 25 + tid];
      lg[tid] = s;
    }
    __syncthreads();
    if (tid == 0) {
      float mx = lg[0];
      for (int l = 1; l < 25; ++l) mx = fmaxf(mx, lg[l]);
      float ss = 0.f;
      for (int l = 0; l < 25; ++l) ss += __expf(lg[l] - mx);
      lg[25] = mx; lg[26] = 1.f / ss;
    }
    __syncthreads();
    if (tid < 25)
      out[((size_t)b * 250 + (t - 1)) * 25 + tid] = __expf(lg[tid] - lg[25]) * lg[26];
  };
  auto caAtt = [&](int t) {
    float* ring = dyn;
    float* bpL  = dyn + 29800;
    float* hid  = dyn + 30152;
    float* kn   = dyn + 30472;
    float* att4 = dyn + 30728;
    float* red  = dyn + 31752;
    float* msum = dyn + 31784;
    float* rvp  = dyn + 31800;
    const int b = bid - 223;
    float* rvD = RVT + (t & 1) * 8192;
    if (tid < 320) {
      float x, y;
      ldpair_sc(&HP0[b * 320 + tid], &HP1[b * 320 + tid], x, y);
      hid[tid] = tanhf(x + y + bpL[tid]);
    }
    __syncthreads();
    if (tid < 256) {
      float v = hid[64 + tid]; float pq = v * v;
      for (int off = 32; off; off >>= 1) pq += __shfl_down(pq, off, 64);
      if ((tid & 63) == 0) red[tid >> 6] = rsqrtf(fmaxf(pq, 1e-12f));
    }
    __syncthreads();
    if (tid < 256) kn[tid] = hid[64 + tid] * red[tid >> 6];
    __syncthreads();
    const int start = (250 - t) % 250;
    if (tid < 500) {
      int m = tid >> 1, dh = tid & 1;
      int p = start + m; if (p >= 250) p -= 250;
      const float* cell = ring + p * 68;
      const float* k0 = kn + dh * 128;
      float n2 = 0.f, d0 = 0.f, d1 = 0.f;
      #pragma unroll
      for (int s = 0; s < 64; s += 4) {
        float4 q = *(const float4*)(cell + s);
        n2 += q.x * q.x + q.y * q.y + q.z * q.z + q.w * q.w;
        d0 += k0[s] * q.x + k0[s + 1] * q.y + k0[s + 2] * q.z + k0[s + 3] * q.w;
        d1 += k0[64 + s] * q.x + k0[64 + s + 1] * q.y + k0[64 + s + 2] * q.z + k0[64 + s + 3] * q.w;
      }
      float rs = rsqrtf(fmaxf(n2, 1e-12f));
      att4[(2 * dh) * 256 + m] = d0 * rs;
      att4[(2 * dh + 1) * 256 + m] = d1 * rs;
    }
    __syncthreads();
    {
      int h4 = tid >> 7, mm = tid & 127;
      float v0 = att4[h4 * 256 + mm];
      bool has2 = (mm + 128) < 250;
      float v1 = has2 ? att4[h4 * 256 + mm + 128] : -3.0e38f;
      float mx = fmaxf(v0, v1);
      for (int off = 32; off; off >>= 1) mx = fmaxf(mx, __shfl_down(mx, off, 64));
      if ((tid & 63) == 0) red[tid >> 6] = mx;
      __syncthreads();
      float MX = fmaxf(red[h4 * 2], red[h4 * 2 + 1]);
      float e0 = __expf(v0 - MX);
      float e1 = has2 ? __expf(v1 - MX) : 0.f;
      att4[h4 * 256 + mm] = e0;
      if (has2) att4[h4 * 256 + mm + 128] = e1;
      float sm_ = e0 + e1;
      for (int off = 32; off; off >>= 1) sm_ += __shfl_down(sm_, off, 64);
      if ((tid & 63) == 0) red[8 + (tid >> 6)] = sm_;
      __syncthreads();
      if (tid < 4) msum[tid] = red[8 + tid * 2] + red[8 + tid * 2 + 1];
      __syncthreads();
    }
    {
      int h4 = tid >> 7, mh = (tid >> 4) & 7, s4 = tid & 15;
      float4 a = {0.f, 0.f, 0.f, 0.f};
      for (int m = mh; m < 250; m += 8) {
        int p = start + m; if (p >= 250) p -= 250;
        float w = att4[h4 * 256 + m];
        float4 q = *(const float4*)(ring + p * 68 + s4 * 4);
        a.x = fmaf(w, q.x, a.x); a.y = fmaf(w, q.y, a.y);
        a.z = fmaf(w, q.z, a.z); a.w = fmaf(w, q.w, a.w);
      }
      *(float4*)(rvp + tid * 4) = a;
    }
    __syncthreads();
    if (tid < 256) {
      int h = tid >> 6, s = tid & 63;
      float sum = 0.f;
      #pragma unroll
      for (int j = 0; j < 8; ++j)
        sum += rvp[(h * 128 + j * 16 + (s >> 2)) * 4 + (s & 3)];
      st_sc(&rvD[(h * 64 + s) * 32 + b], sum / msum[h]);
    }
    __syncthreads();
    if (tid < 64) {
      int ip = start + 249; if (ip >= 250) ip -= 250;
      ring[ip * 68 + tid] = hid[tid];
    }
  };

  // ---------------- dataflow role loops ----------------
  if (bid < 64) {                       // AZ
    azX(0);
    for (int t = 0; t < 250; ++t) {
      waitC(CZP, 96 * (t + 1));
      if (t >= 1) waitC(CRV, 32 * t);
      if (t >= 2) waitC(COH, 32 * (t - 1));   // OL/OHI_{t-2} done (HT WAR)
      azGates(t);
      bumpC(CHT);
      if (t < 249) azX(t + 1);
    }
  } else if (bid < 80) {                // AO
    for (int t = 1; t <= 250; ++t) {
      waitC(CRV, 32 * t);
      waitC(COH, 32 * t);
      aoOut(t);
      bumpC(COP);
    }
  } else if (bid < 144) {               // BL: produce ZP_s, s=0..249
    blLoadLab(0);
    blGemm(0);
    bumpC(CZP);
    for (int t = 0; t <= 248; ++t) {
      blLoadLab(t + 1);
      waitC(CHT, 64 * (t + 1));
      blGemm(t + 1);
      bumpC(CZP);
    }
  } else if (bid < 176) {               // BH
    bhGemm(0);
    bumpC(CZP);
    for (int t = 0; t <= 248; ++t) {
      waitC(CHT, 64 * (t + 1));
      bhGemm(t + 1);
      bumpC(CZP);
    }
  } else if (bid < 223) {               // OL/OHI (OH_t) and PL/PHI (HP_t)
    const bool isOH = bid < 208 && bid >= 176;
    for (int t = 0; t < 250; ++t) {
      waitC(CHT, 64 * (t + 1));
      if (isOH) {
        if (t >= 2) waitC(COP, 16 * (t - 1));  // AO_{t-1} done (OH WAR)
        p2Gemm(t);
        bumpC(COH);
      } else {
        if (t >= 1) waitC(CRV, 32 * t);        // CA_{t-1} done (HP WAR)
        p2Gemm(t);
        bumpC(CHP);
      }
    }
  } else if (bid < 255) {               // CA
    for (int t = 0; t < 250; ++t) {
      if (t >= 1) { waitC(COP, 16 * t); caOut(t); }
      waitC(CHP, 15 * (t + 1));
      caAtt(t);
      bumpC(CRV);
    }
    waitC(COP, 16 * 250);
    caOut(250);
  }
}

extern "C" void kernel_launch(void* const* d_in, const int* in_sizes, int n_in,
                              void* d_out, int out_size, void* d_ws, size_t ws_size,
                              hipStream_t stream) {
  const float* images = (const float*)d_in[0];
  const int* labels = (const int*)d_in[1];
  const float* k1  = (const float*)d_in[2];
  const float* cb1 = (const float*)d_in[3];
  const float* g1  = (const float*)d_in[4];
  const float* be1 = (const float*)d_in[5];
  const float* mm1 = (const float*)d_in[6];
  const float* mv1 = (const float*)d_in[7];
  const float* k2  = (const float*)d_in[8];
  const float* cb2 = (const float*)d_in[9];
  const float* g2  = (const float*)d_in[10];
  const float* be2 = (const float*)d_in[11];
  const float* mm2 = (const float*)d_in[12];
  const float* mv2 = (const float*)d_in[13];
  const float* k3  = (const float*)d_in[14];
  const float* cb3 = (const float*)d_in[15];
  const float* g3  = (const float*)d_in[16];
  const float* be3 = (const float*)d_in[17];
  const float* mm3 = (const float*)d_in[18];
  const float* mv3 = (const float*)d_in[19];
  const float* Wx  = (const float*)d_in[20];
  const float* Wh  = (const float*)d_in[21];
  const float* bl  = (const float*)d_in[22];
  const float* Wp  = (const float*)d_in[23];
  const float* bp  = (const float*)d_in[24];
  const float* Wo  = (const float*)d_in[25];
  const float* bo  = (const float*)d_in[26];
  const float* Wf  = (const float*)d_in[27];
  const float* bf  = (const float*)d_in[28];
  float* ws = (float*)d_ws;

  hipFuncSetAttribute((const void*)lstm_kernel,
                      hipFuncAttributeMaxDynamicSharedMemorySize, DYN_BYTES);

  // zero activation/state/counter region (ws poisoned 0xAA before each call)
  hipMemsetAsync((char*)d_ws + OFF_ZP0 * sizeof(float), 0,
                 (WS_FLOATS - OFF_ZP0) * sizeof(float), stream);
  prep_kernel<<<1024, 256, 0, stream>>>(Wx, Wh, bl, ws);
  conv_kernel<<<8000, 128, 0, stream>>>(images,
      k1, cb1, g1, be1, mm1, mv1,
      k2, cb2, g2, be2, mm2, mv2,
      k3, cb3, g3, be3, mm3, mv3, ws);
  lstm_kernel<<<256, 512, DYN_BYTES, stream>>>(labels, Wo, bo, Wp, bp, Wf, bf, ws,
                                               (float*)d_out);
}